// Round 5
// baseline (1881.171 us; speedup 1.0000x reference)
//
#include <hip/hip_runtime.h>
#include <math.h>

#define NN 100000
#define NE 3200000
#define NF 512
#define NH 256
#define NC 64
#define KSTEPS 10
#define NB 391        // ceil(NN/256)
#define CAP 96        // max real edges per node (Poisson λ=32 → P(>96) ≈ 1e-19)

// ---- binning params ----
#define NBUK 49       // ceil(NN / 2048) dst-buckets
#define BSH 11        // bucket = dst >> 11 (2048 nodes per bucket)
#define BCAP 70000    // entries per bucket region (E[65536], sigma~253 -> 17 sigma margin)
#define BUF 64        // LDS staging entries per bucket
#define BINB 1024     // bin_k blocks
#define PER 3125      // NE / BINB exactly
#define FITER 8       // binning rounds between flushes (E[fill]=41.8 of 64)

typedef _Float16 half8 __attribute__((ext_vector_type(8)));
typedef _Float16 h4v  __attribute__((ext_vector_type(4)));
typedef _Float16 h8v  __attribute__((ext_vector_type(8)));
typedef float f32x4 __attribute__((ext_vector_type(4)));

static __device__ __forceinline__ long long packDS(int d, int s) {
  return (long long)(((unsigned long long)(unsigned)s << 32) | (unsigned)d);
}

// ---------------- init: cnt=0, bucket cursors=0 ----------------

__global__ __launch_bounds__(256) void init_k(int* cnt, int* cursor) {
  int i = blockIdx.x * 256 + threadIdx.x;
  if (i < NN) cnt[i] = 0;
  if (blockIdx.x == 0 && threadIdx.x < NBUK) cursor[threadIdx.x] = 0;
}

// ---------------- pass 1: bin edges by coarse dst range ----------------
// Each edge read ONCE (25.6 MB). LDS-staged appends flush as contiguous
// 512-B bursts (full lines) into per-bucket runs -> ~1x write amplification.
// R4 lesson: scattered 4-B stores cost ~44 B/edge HBM regardless of L2
// residency; FULL-LINE writes are the only fix. R2 bug fixed here: flush
// stride is 4 (block has 4 waves), so every bucket is flushed.

__global__ __launch_bounds__(256) void bin_k(const int* __restrict__ dstI, const int* __restrict__ srcI,
                                             int* __restrict__ cursor, long long* __restrict__ bucket) {
  __shared__ long long buf[NBUK][BUF];   // 25088 B
  __shared__ int bcnt[NBUK];
  const int t    = threadIdx.x;
  const int wave = t >> 6;
  const int lane = t & 63;
  if (t < NBUK) bcnt[t] = 0;
  __syncthreads();

  int eBeg = blockIdx.x * PER;
  int eEnd = eBeg + PER; if (eEnd > NE) eEnd = NE;

  for (int base = eBeg; base < eEnd; base += 256 * FITER) {
    #pragma unroll
    for (int it = 0; it < FITER; ++it) {
      int e = base + it * 256 + t;
      if (e < eEnd) {
        int d = __builtin_nontemporal_load(&dstI[e]);
        int s = __builtin_nontemporal_load(&srcI[e]);
        int b = d >> BSH;
        int pos = atomicAdd(&bcnt[b], 1);
        if (pos < BUF) {
          buf[b][pos] = packDS(d, s);
        } else {                                   // rare overflow: direct append
          int g = atomicAdd(&cursor[b], 1);
          if (g < BCAP) bucket[(size_t)b * BCAP + g] = packDS(d, s);
        }
      }
    }
    __syncthreads();
    // flush: wave w handles buckets w, w+4, w+8, ... (4 waves per block!)
    for (int b = wave; b < NBUK; b += 4) {
      int n = bcnt[b]; if (n > BUF) n = BUF;
      int g = 0;
      if (lane == 0 && n > 0) g = atomicAdd(&cursor[b], n);
      g = __shfl(g, 0, 64);
      if (lane < n) {
        int gi = g + lane;
        if (gi < BCAP) bucket[(size_t)b * BCAP + gi] = buf[b][lane];
      }
      if (lane == 0) bcnt[b] = 0;
    }
    __syncthreads();
  }
}

// ---------------- pass 2: scatter within bucket (XCD-pinned) ----------------
// bucket b processed only by blocks with blockIdx%8 == b%8 (co-resident 2048-
// block grid -> stable XCD pinning). Per XCD: ~3.3MB one-shot nt read stream,
// 786KB dirty slot window per bucket. If WRITE_SIZE still shows ~140MB here,
// L2 write-combining of scattered stores is impossible on gfx950 and the
// next step is LDS-staged per-128-node scatter. Also produces degrees in cnt.

__global__ __launch_bounds__(256) void scatter_k(const long long* __restrict__ bucket, const int* __restrict__ cursor,
                                                 int* __restrict__ cnt, int* __restrict__ slots) {
  int xcd = blockIdx.x & 7;
  int ks  = blockIdx.x >> 3;        // 0..255 block-slot within XCD
  for (int b = xcd; b < NBUK; b += 8) {
    int n = cursor[b]; if (n > BCAP) n = BCAP;
    const long long* bp = bucket + (size_t)b * BCAP;
    for (int i = ks * 256 + threadIdx.x; i < n; i += 256 * 256) {
      long long v = __builtin_nontemporal_load(&bp[i]);
      int d = (int)(unsigned)(v & 0xffffffffll);
      int s = (int)(unsigned)((unsigned long long)v >> 32);
      int pos = atomicAdd(&cnt[d], 1);
      if (pos < CAP) slots[(size_t)d * CAP + pos] = s;
    }
  }
}

// pad each row from cnt to its 16-aligned end with the zero-node index NN
__global__ __launch_bounds__(256) void pad_k(const int* __restrict__ cnt, int* __restrict__ slots) {
  int d = blockIdx.x * 256 + threadIdx.x;
  if (d >= NN) return;
  int c = cnt[d];
  int e = (c + 15) & ~15;
  for (int p = c; p < e; ++p) slots[(size_t)d * CAP + p] = NN;
}

// deg = cnt+1 (self-loop): dinv, sqrt(deg), 0.9/deg. Also zeroes the
// zero-node rows of y0/yA/yB (here because bucket storage aliases yA/yB/c0
// and is only dead after scatter_k).
__global__ __launch_bounds__(256) void dinv_k(const int* __restrict__ cnt, float* dinv, float* dsqrt, float* amul,
                                              _Float16* y0, _Float16* yA, _Float16* yB) {
  int i = blockIdx.x * 256 + threadIdx.x;
  if (i < NN) {
    float d = (float)(cnt[i] + 1);
    dinv[i]  = rsqrtf(d);
    dsqrt[i] = sqrtf(d);
    amul[i]  = 0.9f / d;
  }
  if (blockIdx.x == 0) {
    int t = threadIdx.x;
    if (t < 64)       y0[(size_t)NN * NC + t] = (_Float16)0.f;
    else if (t < 128) yA[(size_t)NN * NC + (t - 64)] = (_Float16)0.f;
    else if (t < 192) yB[(size_t)NN * NC + (t - 128)] = (_Float16)0.f;
  }
}

// ---------------- weight transpose + fp16 convert ----------------

__global__ __launch_bounds__(256) void cvtW1T_k(const float* __restrict__ W1, _Float16* __restrict__ W1T) {
  int t = blockIdx.x * 256 + threadIdx.x;            // 131072
  int n = t >> 9, k = t & 511;
  W1T[t] = (_Float16)W1[k * NH + n];                 // W1T[n][k] = W1[k][n]
}

__global__ __launch_bounds__(256) void cvtW2T_k(const float* __restrict__ W2, _Float16* __restrict__ W2T) {
  int t = blockIdx.x * 256 + threadIdx.x;            // 16384
  int n = t >> 8, k = t & 255;
  W2T[t] = (_Float16)W2[k * NC + n];                 // W2T[n][k] = W2[k][n]
}

// ---------------- fused 2-layer MLP via f16 MFMA ----------------
// outputs y0 = dinv*h0 and c0 = 0.1*dinv*h0 (both fp16, node-major)

__global__ __launch_bounds__(256) void mlp_k(const float* __restrict__ x, const _Float16* __restrict__ W1T,
                                             const float* __restrict__ b1, const _Float16* __restrict__ W2T,
                                             const float* __restrict__ b2, const float* __restrict__ dinv,
                                             _Float16* __restrict__ y0, _Float16* __restrict__ c0) {
  __shared__ _Float16 smem[16896];          // 33792 B
  _Float16* As = smem;                      // [64][40]
  _Float16* Bs = smem + 64 * 40;            // [256][40]
  _Float16* Hs = smem;                      // [64][264] (reuses As/Bs space)

  const int t    = threadIdx.x;
  const int wave = t >> 6;
  const int lane = t & 63;
  const int l15  = lane & 15;
  const int q    = lane >> 4;
  const int m0   = blockIdx.x * 64;

  f32x4 acc[4][4] = {};

  for (int kk = 0; kk < NF; kk += 32) {
    __syncthreads();                        // prev-iter LDS reads done before overwrite
    { // stage A: x[m0..m0+64)[kk..kk+32) -> fp16 As
      int row = t >> 2;
      int kq  = (t & 3) << 3;
      int gr  = m0 + row;
      float4 v0 = make_float4(0.f, 0.f, 0.f, 0.f), v1 = v0;
      if (gr < NN) {
        const float* xp = &x[(size_t)gr * NF + kk + kq];
        v0 = *(const float4*)xp;
        v1 = *(const float4*)(xp + 4);
      }
      half8 hv;
      hv[0] = (_Float16)v0.x; hv[1] = (_Float16)v0.y; hv[2] = (_Float16)v0.z; hv[3] = (_Float16)v0.w;
      hv[4] = (_Float16)v1.x; hv[5] = (_Float16)v1.y; hv[6] = (_Float16)v1.z; hv[7] = (_Float16)v1.w;
      *(half8*)&As[row * 40 + kq] = hv;
    }
    // stage B: W1T[0..256)[kk..kk+32) -> Bs
    #pragma unroll
    for (int i = 0; i < 4; ++i) {
      int idx = t + (i << 8);
      int n   = idx >> 2;
      int kq  = (idx & 3) << 3;
      *(half8*)&Bs[n * 40 + kq] = *(const half8*)&W1T[(size_t)n * NF + kk + kq];
    }
    __syncthreads();
    half8 af[4], bf[4];
    #pragma unroll
    for (int mi = 0; mi < 4; ++mi) af[mi] = *(half8*)&As[(mi * 16 + l15) * 40 + q * 8];
    #pragma unroll
    for (int ni = 0; ni < 4; ++ni) bf[ni] = *(half8*)&Bs[(wave * 64 + ni * 16 + l15) * 40 + q * 8];
    #pragma unroll
    for (int mi = 0; mi < 4; ++mi)
      #pragma unroll
      for (int ni = 0; ni < 4; ++ni)
        acc[mi][ni] = __builtin_amdgcn_mfma_f32_16x16x32_f16(af[mi], bf[ni], acc[mi][ni], 0, 0, 0);
  }
  __syncthreads();   // all As/Bs reads complete -> safe to reuse as Hs

  // epilogue 1: bias + relu -> Hs fp16  (C/D: col=lane&15, row=q*4+reg)
  #pragma unroll
  for (int mi = 0; mi < 4; ++mi) {
    #pragma unroll
    for (int ni = 0; ni < 4; ++ni) {
      int ch = wave * 64 + ni * 16 + l15;
      float bb = b1[ch];
      #pragma unroll
      for (int r = 0; r < 4; ++r) {
        int m = mi * 16 + q * 4 + r;
        float v = acc[mi][ni][r] + bb;
        Hs[m * 264 + ch] = (_Float16)(v > 0.f ? v : 0.f);
      }
    }
  }
  __syncthreads();

  // GEMM2: h0[64x64] = Hs[64x256] @ W2 (+b2); wave w -> cols [16w, 16w+16)
  f32x4 acc2[4] = {};
  for (int kt = 0; kt < 8; ++kt) {
    half8 bf2 = *(const half8*)&W2T[(size_t)(wave * 16 + l15) * NH + kt * 32 + q * 8];
    #pragma unroll
    for (int mi = 0; mi < 4; ++mi) {
      half8 af2 = *(half8*)&Hs[(mi * 16 + l15) * 264 + kt * 32 + q * 8];
      acc2[mi] = __builtin_amdgcn_mfma_f32_16x16x32_f16(af2, bf2, acc2[mi], 0, 0, 0);
    }
  }
  int c = wave * 16 + l15;
  float bb2 = b2[c];
  #pragma unroll
  for (int mi = 0; mi < 4; ++mi)
    #pragma unroll
    for (int r = 0; r < 4; ++r) {
      int m = m0 + mi * 16 + q * 4 + r;
      if (m < NN) {
        float hv = acc2[mi][r] + bb2;
        float dv = dinv[m];
        y0[(size_t)m * NC + c] = (_Float16)(dv * hv);
        c0[(size_t)m * NC + c] = (_Float16)(0.1f * dv * hv);
      }
    }
}

// ---------------- APPNP propagation step on y = dinv*h ----------------
// one wave per node. Eighth-wave (8 lanes x 16B) covers one 128B row ->
// 8 edges per gather instruction (dwordx4); TWO independent gathers per
// loop iteration (R4 lesson: appnp is latency-bound; halving in-flight
// gathers cost ~9 µs/dispatch). Slot rows 16-padded with zero-node NN.

__global__ __launch_bounds__(256) void appnp_k(const _Float16* __restrict__ y_in, const _Float16* __restrict__ c0,
                                               _Float16* __restrict__ y_out,
                                               const int* __restrict__ cnt, const int* __restrict__ slots,
                                               const float* __restrict__ amul) {
  const int lane = threadIdx.x & 63;
  const int g    = lane >> 3;          // edge sub-slot within group of 8
  const int fc   = lane & 7;           // feature chunk: feats 8*fc .. 8*fc+7
  int node = blockIdx.x * 4 + (threadIdx.x >> 6);
  node = __builtin_amdgcn_readfirstlane(node);   // wave-uniform
  const int pcnt = (cnt[node] + 15) & ~15;
  const int* row = slots + (size_t)node * CAP;
  const char* yb = (const char*)y_in;
  const unsigned foff = (unsigned)fc * 16u;

  h8v acc = { (_Float16)0.f, (_Float16)0.f, (_Float16)0.f, (_Float16)0.f,
              (_Float16)0.f, (_Float16)0.f, (_Float16)0.f, (_Float16)0.f };
  for (int e = 0; e < pcnt; e += 16) {
    #pragma unroll
    for (int j = 0; j < 2; ++j) {
      int idx = row[e + j * 8 + g];                        // 32B line per wave, broadcast per group
      unsigned off = (unsigned)idx * 128u + foff;          // v_mad_u32_u24
      acc += *(const h8v*)(yb + off);                      // dwordx4 gather + 4x v_pk_add_f16
    }
  }

  // reduce across the 8 groups (lanes with same fc): xor 8, 16, 32
  #pragma unroll
  for (int d = 8; d <= 32; d <<= 1) {
    int4 ai = *(int4*)&acc;
    int4 o;
    o.x = __shfl_xor(ai.x, d, 64);
    o.y = __shfl_xor(ai.y, d, 64);
    o.z = __shfl_xor(ai.z, d, 64);
    o.w = __shfl_xor(ai.w, d, 64);
    acc += *(h8v*)&o;
  }

  if (g == 0) {
    // self-loop + c0 + amul scale, in fp32
    size_t rowb = (size_t)node * 128 + foff;
    h8v self = *(const h8v*)((const char*)y_in + rowb);
    h8v cc   = *(const h8v*)((const char*)c0   + rowb);
    float am = amul[node];
    h8v r;
    #pragma unroll
    for (int i = 0; i < 8; ++i)
      r[i] = (_Float16)(am * ((float)acc[i] + (float)self[i]) + (float)cc[i]);
    *(h8v*)((char*)y_out + rowb) = r;
  }
}

// ---------------- log_softmax (recover h = y * sqrt(deg)) ----------------

__global__ __launch_bounds__(256) void lsm_k(const _Float16* __restrict__ y, const float* __restrict__ dsqrt,
                                             float* __restrict__ out) {
  int lane = threadIdx.x & 63;
  int node = blockIdx.x * 4 + (threadIdx.x >> 6);
  node = __builtin_amdgcn_readfirstlane(node);
  float v = (float)y[(size_t)node * NC + lane] * dsqrt[node];
  float m = v;
  #pragma unroll
  for (int off = 32; off > 0; off >>= 1) m = fmaxf(m, __shfl_xor(m, off, 64));
  float e = expf(v - m);
  float s = e;
  #pragma unroll
  for (int off = 32; off > 0; off >>= 1) s += __shfl_xor(s, off, 64);
  out[(size_t)node * NC + lane] = (v - m) - logf(s);
}

// ---------------- launch ----------------

extern "C" void kernel_launch(void* const* d_in, const int* in_sizes, int n_in,
                              void* d_out, int out_size, void* d_ws, size_t ws_size,
                              hipStream_t stream) {
  (void)in_sizes; (void)n_in; (void)out_size; (void)ws_size;
  const float* x  = (const float*)d_in[0];
  const int*   ei = (const int*)d_in[1];
  const float* W1 = (const float*)d_in[2];
  const float* b1 = (const float*)d_in[3];
  const float* W2 = (const float*)d_in[4];
  const float* b2 = (const float*)d_in[5];
  float* out = (float*)d_out;

  const int* srcI = ei;        // edge_index[0] = message source
  const int* dstI = ei + NE;   // edge_index[1] = aggregation target

  char* p = (char*)d_ws;
  auto carve = [&](size_t bytes) -> void* {
    void* q = (void*)p;
    p += (bytes + 255) & ~(size_t)255;
    return q;
  };
  _Float16* y0   = (_Float16*)carve((size_t)(NN + 1) * NC * 2);
  _Float16* yA   = (_Float16*)carve((size_t)(NN + 1) * NC * 2);
  _Float16* yB   = (_Float16*)carve((size_t)(NN + 1) * NC * 2);
  _Float16* c0   = (_Float16*)carve((size_t)NN * NC * 2);
  _Float16* W1T  = (_Float16*)carve((size_t)NH * NF * 2);
  _Float16* W2T  = (_Float16*)carve((size_t)NC * NH * 2);
  float* dinv    = (float*)carve((size_t)NN * 4);
  float* dsqrt   = (float*)carve((size_t)NN * 4);
  float* amul    = (float*)carve((size_t)NN * 4);
  int*   cnt     = (int*)carve((size_t)NN * 4);
  int*   slots   = (int*)carve((size_t)NN * CAP * 4);
  int*   cursor  = (int*)carve((size_t)NBUK * 4);

  // bucket storage (NBUK*BCAP*8 = 27.44MB) aliases yA..c0 (38.4MB); buckets
  // are dead after scatter_k, before mlp_k writes c0/y0 and dinv_k zeroes rows.
  long long* bucket = (long long*)yA;

  init_k   <<<NB, 256, 0, stream>>>(cnt, cursor);
  bin_k    <<<BINB, 256, 0, stream>>>(dstI, srcI, cursor, bucket);
  scatter_k<<<2048, 256, 0, stream>>>(bucket, cursor, cnt, slots);
  pad_k    <<<NB, 256, 0, stream>>>(cnt, slots);
  dinv_k   <<<NB, 256, 0, stream>>>(cnt, dinv, dsqrt, amul, y0, yA, yB);
  cvtW1T_k <<<(NH * NF) / 256, 256, 0, stream>>>(W1, W1T);
  cvtW2T_k <<<(NC * NH) / 256, 256, 0, stream>>>(W2, W2T);
  mlp_k    <<<(NN + 63) / 64, 256, 0, stream>>>(x, W1T, b1, W2T, b2, dinv, y0, c0);

  const _Float16* yin = y0;
  _Float16* bufs[2] = { yA, yB };
  for (int it = 0; it < KSTEPS; ++it) {
    _Float16* yo = bufs[it & 1];
    appnp_k<<<NN / 4, 256, 0, stream>>>(yin, c0, yo, cnt, slots, amul);
    yin = yo;
  }
  lsm_k<<<NN / 4, 256, 0, stream>>>(yin, dsqrt, out);
}

// Round 6
// 1046.500 us; speedup vs baseline: 1.7976x; 1.7976x over previous
//
#include <hip/hip_runtime.h>
#include <math.h>

#define NN 100000
#define NE 3200000
#define NF 512
#define NH 256
#define NC 64
#define KSTEPS 10
#define NB 391        // ceil(NN/256)
#define CAP 96        // max real edges per node (Poisson λ=32 → P(>96) ≈ 1e-19)
#define NPH 8         // fill phases (dst ranges of 12500 nodes)
#define FBP 1024      // fill blocks per phase
#define PHD 4         // phases per fill dispatch (2 dispatches; each ~72µs so
                      // appnp_k surfaces in rocprof top-5 for diagnosis)

typedef _Float16 half8 __attribute__((ext_vector_type(8)));
typedef _Float16 h4v  __attribute__((ext_vector_type(4)));
typedef _Float16 h8v  __attribute__((ext_vector_type(8)));
typedef float f32x4 __attribute__((ext_vector_type(4)));

// ---------------- init: cnt=0, zero-node rows of y buffers ----------------

__global__ __launch_bounds__(256) void init_k(int* cnt, _Float16* y0, _Float16* yA, _Float16* yB) {
  int i = blockIdx.x * 256 + threadIdx.x;
  if (i < NN) cnt[i] = 0;
  if (blockIdx.x == 0) {
    int t = threadIdx.x;
    if (t < 64)       y0[(size_t)NN * NC + t] = (_Float16)0.f;
    else if (t < 128) yA[(size_t)NN * NC + (t - 64)] = (_Float16)0.f;
    else if (t < 192) yB[(size_t)NN * NC + (t - 128)] = (_Float16)0.f;
  }
}

// ---------------- single-pass slot fill (R3 proven form) ----------------
// R4/R5 lessons: scattered 4-B stores cost ~44 B/edge HBM regardless of L2
// residency games (write-combining of scattered stores does not happen),
// and the LDS-binning alternative stalls 99.6% for unidentified reasons.
// This form (145 µs/dispatch-equivalent) is the accepted cost.

__global__ __launch_bounds__(256) void fill_k(const int* __restrict__ dstI, const int* __restrict__ srcI,
                                              int* __restrict__ cnt, int* __restrict__ slots, int phBase) {
  int ph = phBase + (blockIdx.x & (PHD - 1));
  int bi = blockIdx.x >> 2;                 // 0..FBP-1
  int lo = ph * (NN / NPH);
  int hi = lo + (NN / NPH);
  for (int e = bi * 256 + threadIdx.x; e < NE; e += FBP * 256) {
    int d = __builtin_nontemporal_load(&dstI[e]);
    if (d >= lo && d < hi) {
      int s = __builtin_nontemporal_load(&srcI[e]);
      int pos = atomicAdd(&cnt[d], 1);
      if (pos < CAP) slots[(size_t)d * CAP + pos] = s;
    }
  }
}

// pad each row from cnt to its 16-aligned end with the zero-node index NN
__global__ __launch_bounds__(256) void pad_k(const int* __restrict__ cnt, int* __restrict__ slots) {
  int d = blockIdx.x * 256 + threadIdx.x;
  if (d >= NN) return;
  int c = cnt[d];
  int e = (c + 15) & ~15;
  for (int p = c; p < e; ++p) slots[(size_t)d * CAP + p] = NN;
}

// deg = cnt+1 (self-loop): dinv, sqrt(deg), 0.9/deg
__global__ __launch_bounds__(256) void dinv_k(const int* __restrict__ cnt, float* dinv, float* dsqrt, float* amul) {
  int i = blockIdx.x * 256 + threadIdx.x;
  if (i < NN) {
    float d = (float)(cnt[i] + 1);
    dinv[i]  = rsqrtf(d);
    dsqrt[i] = sqrtf(d);
    amul[i]  = 0.9f / d;
  }
}

// ---------------- weight transpose + fp16 convert ----------------

__global__ __launch_bounds__(256) void cvtW1T_k(const float* __restrict__ W1, _Float16* __restrict__ W1T) {
  int t = blockIdx.x * 256 + threadIdx.x;            // 131072
  int n = t >> 9, k = t & 511;
  W1T[t] = (_Float16)W1[k * NH + n];                 // W1T[n][k] = W1[k][n]
}

__global__ __launch_bounds__(256) void cvtW2T_k(const float* __restrict__ W2, _Float16* __restrict__ W2T) {
  int t = blockIdx.x * 256 + threadIdx.x;            // 16384
  int n = t >> 8, k = t & 255;
  W2T[t] = (_Float16)W2[k * NC + n];                 // W2T[n][k] = W2[k][n]
}

// ---------------- fused 2-layer MLP via f16 MFMA ----------------
// outputs y0 = dinv*h0 and c0 = 0.1*dinv*h0 (both fp16, node-major)

__global__ __launch_bounds__(256) void mlp_k(const float* __restrict__ x, const _Float16* __restrict__ W1T,
                                             const float* __restrict__ b1, const _Float16* __restrict__ W2T,
                                             const float* __restrict__ b2, const float* __restrict__ dinv,
                                             _Float16* __restrict__ y0, _Float16* __restrict__ c0) {
  __shared__ _Float16 smem[16896];          // 33792 B
  _Float16* As = smem;                      // [64][40]
  _Float16* Bs = smem + 64 * 40;            // [256][40]
  _Float16* Hs = smem;                      // [64][264] (reuses As/Bs space)

  const int t    = threadIdx.x;
  const int wave = t >> 6;
  const int lane = t & 63;
  const int l15  = lane & 15;
  const int q    = lane >> 4;
  const int m0   = blockIdx.x * 64;

  f32x4 acc[4][4] = {};

  for (int kk = 0; kk < NF; kk += 32) {
    __syncthreads();                        // prev-iter LDS reads done before overwrite
    { // stage A: x[m0..m0+64)[kk..kk+32) -> fp16 As
      int row = t >> 2;
      int kq  = (t & 3) << 3;
      int gr  = m0 + row;
      float4 v0 = make_float4(0.f, 0.f, 0.f, 0.f), v1 = v0;
      if (gr < NN) {
        const float* xp = &x[(size_t)gr * NF + kk + kq];
        v0 = *(const float4*)xp;
        v1 = *(const float4*)(xp + 4);
      }
      half8 hv;
      hv[0] = (_Float16)v0.x; hv[1] = (_Float16)v0.y; hv[2] = (_Float16)v0.z; hv[3] = (_Float16)v0.w;
      hv[4] = (_Float16)v1.x; hv[5] = (_Float16)v1.y; hv[6] = (_Float16)v1.z; hv[7] = (_Float16)v1.w;
      *(half8*)&As[row * 40 + kq] = hv;
    }
    // stage B: W1T[0..256)[kk..kk+32) -> Bs
    #pragma unroll
    for (int i = 0; i < 4; ++i) {
      int idx = t + (i << 8);
      int n   = idx >> 2;
      int kq  = (idx & 3) << 3;
      *(half8*)&Bs[n * 40 + kq] = *(const half8*)&W1T[(size_t)n * NF + kk + kq];
    }
    __syncthreads();
    half8 af[4], bf[4];
    #pragma unroll
    for (int mi = 0; mi < 4; ++mi) af[mi] = *(half8*)&As[(mi * 16 + l15) * 40 + q * 8];
    #pragma unroll
    for (int ni = 0; ni < 4; ++ni) bf[ni] = *(half8*)&Bs[(wave * 64 + ni * 16 + l15) * 40 + q * 8];
    #pragma unroll
    for (int mi = 0; mi < 4; ++mi)
      #pragma unroll
      for (int ni = 0; ni < 4; ++ni)
        acc[mi][ni] = __builtin_amdgcn_mfma_f32_16x16x32_f16(af[mi], bf[ni], acc[mi][ni], 0, 0, 0);
  }
  __syncthreads();   // all As/Bs reads complete -> safe to reuse as Hs

  // epilogue 1: bias + relu -> Hs fp16  (C/D: col=lane&15, row=q*4+reg)
  #pragma unroll
  for (int mi = 0; mi < 4; ++mi) {
    #pragma unroll
    for (int ni = 0; ni < 4; ++ni) {
      int ch = wave * 64 + ni * 16 + l15;
      float bb = b1[ch];
      #pragma unroll
      for (int r = 0; r < 4; ++r) {
        int m = mi * 16 + q * 4 + r;
        float v = acc[mi][ni][r] + bb;
        Hs[m * 264 + ch] = (_Float16)(v > 0.f ? v : 0.f);
      }
    }
  }
  __syncthreads();

  // GEMM2: h0[64x64] = Hs[64x256] @ W2 (+b2); wave w -> cols [16w, 16w+16)
  f32x4 acc2[4] = {};
  for (int kt = 0; kt < 8; ++kt) {
    half8 bf2 = *(const half8*)&W2T[(size_t)(wave * 16 + l15) * NH + kt * 32 + q * 8];
    #pragma unroll
    for (int mi = 0; mi < 4; ++mi) {
      half8 af2 = *(half8*)&Hs[(mi * 16 + l15) * 264 + kt * 32 + q * 8];
      acc2[mi] = __builtin_amdgcn_mfma_f32_16x16x32_f16(af2, bf2, acc2[mi], 0, 0, 0);
    }
  }
  int c = wave * 16 + l15;
  float bb2 = b2[c];
  #pragma unroll
  for (int mi = 0; mi < 4; ++mi)
    #pragma unroll
    for (int r = 0; r < 4; ++r) {
      int m = m0 + mi * 16 + q * 4 + r;
      if (m < NN) {
        float hv = acc2[mi][r] + bb2;
        float dv = dinv[m];
        y0[(size_t)m * NC + c] = (_Float16)(dv * hv);
        c0[(size_t)m * NC + c] = (_Float16)(0.1f * dv * hv);
      }
    }
}

// ---------------- APPNP propagation step on y = dinv*h (R3 proven form) ----
// one wave per node. Eighth-wave (8 lanes x 16B) covers one 128B row ->
// 8 edges per gather instruction (dwordx4); TWO independent gathers per
// loop iteration (R4 lesson: latency-bound, keep >=2 in flight).

__global__ __launch_bounds__(256) void appnp_k(const _Float16* __restrict__ y_in, const _Float16* __restrict__ c0,
                                               _Float16* __restrict__ y_out,
                                               const int* __restrict__ cnt, const int* __restrict__ slots,
                                               const float* __restrict__ amul) {
  const int lane = threadIdx.x & 63;
  const int g    = lane >> 3;          // edge sub-slot within group of 8
  const int fc   = lane & 7;           // feature chunk: feats 8*fc .. 8*fc+7
  int node = blockIdx.x * 4 + (threadIdx.x >> 6);
  node = __builtin_amdgcn_readfirstlane(node);   // wave-uniform
  const int pcnt = (cnt[node] + 15) & ~15;
  const int* row = slots + (size_t)node * CAP;
  const char* yb = (const char*)y_in;
  const unsigned foff = (unsigned)fc * 16u;

  h8v acc = { (_Float16)0.f, (_Float16)0.f, (_Float16)0.f, (_Float16)0.f,
              (_Float16)0.f, (_Float16)0.f, (_Float16)0.f, (_Float16)0.f };
  for (int e = 0; e < pcnt; e += 16) {
    #pragma unroll
    for (int j = 0; j < 2; ++j) {
      int idx = row[e + j * 8 + g];                        // 32B line per wave, broadcast per group
      unsigned off = (unsigned)idx * 128u + foff;          // v_mad_u32_u24
      acc += *(const h8v*)(yb + off);                      // dwordx4 gather + 4x v_pk_add_f16
    }
  }

  // reduce across the 8 groups (lanes with same fc): xor 8, 16, 32
  #pragma unroll
  for (int d = 8; d <= 32; d <<= 1) {
    int4 ai = *(int4*)&acc;
    int4 o;
    o.x = __shfl_xor(ai.x, d, 64);
    o.y = __shfl_xor(ai.y, d, 64);
    o.z = __shfl_xor(ai.z, d, 64);
    o.w = __shfl_xor(ai.w, d, 64);
    acc += *(h8v*)&o;
  }

  if (g == 0) {
    // self-loop + c0 + amul scale, in fp32
    size_t rowb = (size_t)node * 128 + foff;
    h8v self = *(const h8v*)((const char*)y_in + rowb);
    h8v cc   = *(const h8v*)((const char*)c0   + rowb);
    float am = amul[node];
    h8v r;
    #pragma unroll
    for (int i = 0; i < 8; ++i)
      r[i] = (_Float16)(am * ((float)acc[i] + (float)self[i]) + (float)cc[i]);
    *(h8v*)((char*)y_out + rowb) = r;
  }
}

// ---------------- final APPNP step with fused log_softmax ----------------
// identical gather/reduce; epilogue computes y (rounded through fp16 to match
// the unfused numerics), h = y*sqrt(deg), and log_softmax over the 64 feats
// held by the 8 lanes of group 0 (8 feats/lane; shfl_xor 1,2,4 reduces).
// Skips the y_out store and the separate lsm pass entirely.

__global__ __launch_bounds__(256) void appnp_last_k(const _Float16* __restrict__ y_in, const _Float16* __restrict__ c0,
                                                    const int* __restrict__ cnt, const int* __restrict__ slots,
                                                    const float* __restrict__ amul, const float* __restrict__ dsqrt,
                                                    float* __restrict__ out) {
  const int lane = threadIdx.x & 63;
  const int g    = lane >> 3;
  const int fc   = lane & 7;
  int node = blockIdx.x * 4 + (threadIdx.x >> 6);
  node = __builtin_amdgcn_readfirstlane(node);
  const int pcnt = (cnt[node] + 15) & ~15;
  const int* row = slots + (size_t)node * CAP;
  const char* yb = (const char*)y_in;
  const unsigned foff = (unsigned)fc * 16u;

  h8v acc = { (_Float16)0.f, (_Float16)0.f, (_Float16)0.f, (_Float16)0.f,
              (_Float16)0.f, (_Float16)0.f, (_Float16)0.f, (_Float16)0.f };
  for (int e = 0; e < pcnt; e += 16) {
    #pragma unroll
    for (int j = 0; j < 2; ++j) {
      int idx = row[e + j * 8 + g];
      unsigned off = (unsigned)idx * 128u + foff;
      acc += *(const h8v*)(yb + off);
    }
  }
  #pragma unroll
  for (int d = 8; d <= 32; d <<= 1) {
    int4 ai = *(int4*)&acc;
    int4 o;
    o.x = __shfl_xor(ai.x, d, 64);
    o.y = __shfl_xor(ai.y, d, 64);
    o.z = __shfl_xor(ai.z, d, 64);
    o.w = __shfl_xor(ai.w, d, 64);
    acc += *(h8v*)&o;
  }

  if (g == 0) {
    size_t rowb = (size_t)node * 128 + foff;
    h8v self = *(const h8v*)((const char*)y_in + rowb);
    h8v cc   = *(const h8v*)((const char*)c0   + rowb);
    float am  = amul[node];
    float dsq = dsqrt[node];
    float v[8];
    #pragma unroll
    for (int i = 0; i < 8; ++i) {
      _Float16 yh = (_Float16)(am * ((float)acc[i] + (float)self[i]) + (float)cc[i]);
      v[i] = (float)yh * dsq;
    }
    // max over the row: lane-local then across the 8 lanes of group 0
    float m = v[0];
    #pragma unroll
    for (int i = 1; i < 8; ++i) m = fmaxf(m, v[i]);
    #pragma unroll
    for (int off = 1; off <= 4; off <<= 1) m = fmaxf(m, __shfl_xor(m, off, 64));
    float s = 0.f;
    #pragma unroll
    for (int i = 0; i < 8; ++i) s += expf(v[i] - m);
    #pragma unroll
    for (int off = 1; off <= 4; off <<= 1) s += __shfl_xor(s, off, 64);
    float ls = logf(s);
    f32x4 o0, o1;
    #pragma unroll
    for (int i = 0; i < 4; ++i) { o0[i] = (v[i] - m) - ls; o1[i] = (v[i + 4] - m) - ls; }
    float* op = out + (size_t)node * NC + fc * 8;
    *(f32x4*)op       = o0;
    *(f32x4*)(op + 4) = o1;
  }
}

// ---------------- launch ----------------

extern "C" void kernel_launch(void* const* d_in, const int* in_sizes, int n_in,
                              void* d_out, int out_size, void* d_ws, size_t ws_size,
                              hipStream_t stream) {
  (void)in_sizes; (void)n_in; (void)out_size; (void)ws_size;
  const float* x  = (const float*)d_in[0];
  const int*   ei = (const int*)d_in[1];
  const float* W1 = (const float*)d_in[2];
  const float* b1 = (const float*)d_in[3];
  const float* W2 = (const float*)d_in[4];
  const float* b2 = (const float*)d_in[5];
  float* out = (float*)d_out;

  const int* srcI = ei;        // edge_index[0] = message source
  const int* dstI = ei + NE;   // edge_index[1] = aggregation target

  char* p = (char*)d_ws;
  auto carve = [&](size_t bytes) -> void* {
    void* q = (void*)p;
    p += (bytes + 255) & ~(size_t)255;
    return q;
  };
  _Float16* y0   = (_Float16*)carve((size_t)(NN + 1) * NC * 2);
  _Float16* yA   = (_Float16*)carve((size_t)(NN + 1) * NC * 2);
  _Float16* yB   = (_Float16*)carve((size_t)(NN + 1) * NC * 2);
  _Float16* c0   = (_Float16*)carve((size_t)NN * NC * 2);
  _Float16* W1T  = (_Float16*)carve((size_t)NH * NF * 2);
  _Float16* W2T  = (_Float16*)carve((size_t)NC * NH * 2);
  float* dinv    = (float*)carve((size_t)NN * 4);
  float* dsqrt   = (float*)carve((size_t)NN * 4);
  float* amul    = (float*)carve((size_t)NN * 4);
  int*   cnt     = (int*)carve((size_t)NN * 4);
  int*   slots   = (int*)carve((size_t)NN * CAP * 4);

  init_k   <<<NB, 256, 0, stream>>>(cnt, y0, yA, yB);
  fill_k   <<<PHD * FBP, 256, 0, stream>>>(dstI, srcI, cnt, slots, 0);
  fill_k   <<<PHD * FBP, 256, 0, stream>>>(dstI, srcI, cnt, slots, PHD);
  pad_k    <<<NB, 256, 0, stream>>>(cnt, slots);
  dinv_k   <<<NB, 256, 0, stream>>>(cnt, dinv, dsqrt, amul);
  cvtW1T_k <<<(NH * NF) / 256, 256, 0, stream>>>(W1, W1T);
  cvtW2T_k <<<(NC * NH) / 256, 256, 0, stream>>>(W2, W2T);
  mlp_k    <<<(NN + 63) / 64, 256, 0, stream>>>(x, W1T, b1, W2T, b2, dinv, y0, c0);

  const _Float16* yin = y0;
  _Float16* bufs[2] = { yA, yB };
  for (int it = 0; it < KSTEPS - 1; ++it) {
    _Float16* yo = bufs[it & 1];
    appnp_k<<<NN / 4, 256, 0, stream>>>(yin, c0, yo, cnt, slots, amul);
    yin = yo;
  }
  appnp_last_k<<<NN / 4, 256, 0, stream>>>(yin, c0, cnt, slots, amul, dsqrt, out);
}